// Round 7
// baseline (837.742 us; speedup 1.0000x reference)
//
#include <hip/hip_runtime.h>

// VQ-VAE vector quantizer, MI355X — MFMA screen (fragment-major, no-LDS) + exact refine.
// z: (4,256,16,32,32) f32 ; emb: (1024,256) f32
// out (f32): z_q_st[16777216] | vq_loss | perplexity | indices[65536]
//
// Exactness contract (validated rounds 2-6, absmax 0):
//   x_sq[n], e_sq[k]: numpy pairwise sum of fl32(v*v) (two 128-blocks, 8 accs)
//   xe[n][k]: single sequential f32 FMA chain over c=0..255
//   d = fl32( fl32(x_sq+e_sq) - 2*xe ), argmin first-min tie-break.
// Screen = bf16-split MFMA (zh*eh + zl*eh + zh*el, 32x32x16, ascending c chain,
// identical accumulation order to round 6); rows with merged gap <= T=4e-4 are
// recomputed by the exact scalar chain (refine). Screen error only flags more.
//
// Round-7: round 6's screen was LDS-bound (14.2M bank-conflict cycles, 4-way on
// b128 frag reads; 18 MB/CU LDS traffic; 2 waves/SIMD). Now zh/zl/eh/el are
// stored FRAGMENT-MAJOR: per (32-row tile, 16-c chunk) the 64 lanes' 16B MFMA
// fragments are contiguous (1 KB). Screen loads fragments straight from global
// (coalesced dwordx4, L1-served), zero LDS in the main loop, zero barriers,
// 2x2 acc tiles/wave, 4 waves/SIMD.

#define C_DIM 256
#define K_CODES 1024
#define N_VEC 65536
#define T_GAP 4e-4f

#define OUT_ZQ_SIZE 16777216
#define OUT_LOSS_OFF 16777216
#define OUT_PP_OFF   16777217
#define OUT_IDX_OFF  16777218

// ws layout (bytes)
#define WS_EH    0          // bf16 frag-major [32 kt][16 q][64 l][8]   512 KB
#define WS_EL    524288     // same                                     512 KB
#define WS_ESQ   1048576    // f32 [1024]
#define WS_XSQ   1052672    // f32 [65536]
#define WS_CNT   1314816    // u32 counts[1024]
#define WS_LOSS  1318912    // f64 loss
#define WS_FLC   1318920    // u32 flag count
#define WS_SIDX  1318928    // i32 screen_idx[65536]
#define WS_FLIST 1581072    // u32 flag_list[65536]
#define WS_PM1   1843264    // f32 [4][65536]
#define WS_EMBT  1843264    // f32 [256][1024] (overlays PM1 after merge)
#define WS_PM2   2891840    // f32 [4][65536]
#define WS_PIX   3940416    // u16 [4][65536]  (ends 4464704)

typedef __attribute__((ext_vector_type(8))) short short8;
typedef __attribute__((ext_vector_type(8))) unsigned short ushort8;
typedef __attribute__((ext_vector_type(16))) float f32x16;

__device__ __forceinline__ unsigned short bf16_rne(float v) {
    unsigned u = __float_as_uint(v);
    unsigned r = (u + 0x7FFFu + ((u >> 16) & 1u)) >> 16;
    return (unsigned short)r;
}

// fragment-major address (in shorts) of element (row, c) within a panel:
//   tile = row>>5, q = c>>4, lane = (row&31) + 32*((c>>3)&1), j = c&7
//   off  = tile*8192 + q*512 + lane*8 + j

// ---------- conversions ----------

__global__ __launch_bounds__(256) void convert_z_kernel(const float* __restrict__ z,
                                                        unsigned short* __restrict__ zhF,
                                                        unsigned short* __restrict__ zlF) {
    const int tid = threadIdx.x;
    const int ln = tid & 63;
    const int og = tid >> 6;
    const int n0 = blockIdx.x * 64;
    const int b = n0 >> 14, s0 = n0 & 16383;
    const int n = n0 + ln;
    const size_t zbase = ((size_t)b << 22) + s0 + ln;
    const size_t tbase = (size_t)(n >> 5) * 8192;
    const int lr = n & 31;
#pragma unroll
    for (int t = 0; t < 8; ++t) {
        int o = og + t * 4;        // c-octet 0..31
        int c0 = o * 8;
        ushort8 hb, lb;
#pragma unroll
        for (int j = 0; j < 8; ++j) {
            float v = z[zbase + ((size_t)(c0 + j) << 14)];
            unsigned short h = bf16_rne(v);
            hb[j] = h;
            lb[j] = bf16_rne(v - __uint_as_float((unsigned)h << 16));
        }
        size_t off = tbase + (size_t)(o >> 1) * 512 + (size_t)(lr + 32 * (o & 1)) * 8;
        *reinterpret_cast<ushort8*>(zhF + off) = hb;
        *reinterpret_cast<ushort8*>(zlF + off) = lb;
    }
}

__global__ __launch_bounds__(256) void convert_e_kernel(const float* __restrict__ emb,
                                                        unsigned short* __restrict__ ehF,
                                                        unsigned short* __restrict__ elF) {
    int t = blockIdx.x * 256 + threadIdx.x;   // 32768 threads
    int k = t >> 5, o = t & 31;
    int c0 = o * 8;
    ushort8 hb, lb;
#pragma unroll
    for (int j = 0; j < 8; ++j) {
        float v = emb[k * C_DIM + c0 + j];
        unsigned short h = bf16_rne(v);
        hb[j] = h;
        lb[j] = bf16_rne(v - __uint_as_float((unsigned)h << 16));
    }
    size_t off = (size_t)(k >> 5) * 8192 + (size_t)(o >> 1) * 512 + (size_t)((k & 31) + 32 * (o & 1)) * 8;
    *reinterpret_cast<ushort8*>(ehF + off) = hb;
    *reinterpret_cast<ushort8*>(elF + off) = lb;
}

// ---------- exact norms (validated) ----------

__device__ __forceinline__ float pairwise_sq_128(const float* p) {
#pragma clang fp contract(off)
    float r[8];
#pragma unroll
    for (int j = 0; j < 8; ++j) { float v = p[j]; r[j] = v * v; }
#pragma unroll
    for (int i = 8; i < 128; i += 8)
#pragma unroll
        for (int j = 0; j < 8; ++j) { float v = p[i + j]; float t = v * v; r[j] = r[j] + t; }
    return ((r[0] + r[1]) + (r[2] + r[3])) + ((r[4] + r[5]) + (r[6] + r[7]));
}

__global__ __launch_bounds__(256) void esq_kernel(const float* __restrict__ emb,
                                                  float* __restrict__ esq) {
#pragma clang fp contract(off)
    __shared__ float tile[64 * 260];
    const int tid = threadIdx.x;
    const int k0 = blockIdx.x * 64;
#pragma unroll
    for (int r = 0; r < 64; ++r) {
        int idx = r * 256 + tid;
        tile[(idx >> 8) * 260 + (idx & 255)] = emb[k0 * C_DIM + idx];
    }
    __syncthreads();
    if (tid < 64) {
        const float* row = &tile[tid * 260];
        esq[k0 + tid] = pairwise_sq_128(row) + pairwise_sq_128(row + 128);
    }
}

__global__ __launch_bounds__(256) void xsq_kernel(const float* __restrict__ z,
                                                  float* __restrict__ xsq) {
#pragma clang fp contract(off)
    const int n = blockIdx.x * 256 + threadIdx.x;
    const int b = n >> 14, s = n & 16383;
    const float* base = z + ((size_t)b << 22) + s;
    float r[8], res;
#pragma unroll
    for (int j = 0; j < 8; ++j) { float v = base[(size_t)j << 14]; r[j] = v * v; }
#pragma unroll
    for (int i = 8; i < 128; i += 8)
#pragma unroll
        for (int j = 0; j < 8; ++j) { float v = base[(size_t)(i + j) << 14]; float t = v * v; r[j] = r[j] + t; }
    res = ((r[0] + r[1]) + (r[2] + r[3])) + ((r[4] + r[5]) + (r[6] + r[7]));
#pragma unroll
    for (int j = 0; j < 8; ++j) { float v = base[(size_t)(128 + j) << 14]; r[j] = v * v; }
#pragma unroll
    for (int i = 136; i < 256; i += 8)
#pragma unroll
        for (int j = 0; j < 8; ++j) { float v = base[(size_t)(i + j) << 14]; float t = v * v; r[j] = r[j] + t; }
    res = res + (((r[0] + r[1]) + (r[2] + r[3])) + ((r[4] + r[5]) + (r[6] + r[7])));
    xsq[n] = res;
}

__global__ __launch_bounds__(256) void transpose_kernel(const float* __restrict__ emb,
                                                        float* __restrict__ embT) {
    __shared__ float t[64][65];
    const int k0 = blockIdx.x * 64;
    const int c0 = blockIdx.y * 64;
    const int tx = threadIdx.x & 63, ty = threadIdx.x >> 6;
    for (int r = ty; r < 64; r += 4)
        t[r][tx] = emb[(k0 + r) * C_DIM + c0 + tx];
    __syncthreads();
    for (int r = ty; r < 64; r += 4)
        embT[(c0 + r) * K_CODES + k0 + tx] = t[tx][r];
}

// ---------- MFMA screen: no-LDS fragment-direct; block 64n x 256k, wave 64n x 64k ----------

__global__ __launch_bounds__(256, 4) void screen_kernel(
    const unsigned short* __restrict__ zhF, const unsigned short* __restrict__ zlF,
    const unsigned short* __restrict__ ehF, const unsigned short* __restrict__ elF,
    const float* __restrict__ esq, const float* __restrict__ xsq,
    float* __restrict__ pm1, float* __restrict__ pm2,
    unsigned short* __restrict__ pix) {
    __shared__ float lm1[4][64], lm2[4][64];
    __shared__ int   li1[4][64];

    const int tid = threadIdx.x;
    const int w = tid >> 6, l = tid & 63, lr = l & 31, lh = l >> 5;
    const int bid = blockIdx.x;
    const int v = (bid & 7) * 512 + (bid >> 3);     // XCD-chunked swizzle (4096 blocks)
    const int nb = v >> 2, kb = v & 3;
    const int n0 = nb * 64;
    const int kw = kb * 256 + w * 64;               // this wave's 64-k window
    const size_t Aoff = (size_t)(n0 >> 5) * 8192;
    const size_t Boff = (size_t)(kw >> 5) * 8192;
    const int loff = l * 8;

    f32x16 a00, a01, a10, a11;
#pragma unroll
    for (int i = 0; i < 16; ++i) { a00[i] = 0.0f; a01[i] = 0.0f; a10[i] = 0.0f; a11[i] = 0.0f; }

    const unsigned short* Ap;
    const unsigned short* Bp;
#define QLOOP                                                                           \
    _Pragma("unroll")                                                                   \
    for (int q = 0; q < 16; ++q) {                                                      \
        short8 fa0 = *reinterpret_cast<const short8*>(Ap + q * 512 + loff);             \
        short8 fa1 = *reinterpret_cast<const short8*>(Ap + 8192 + q * 512 + loff);      \
        short8 fb0 = *reinterpret_cast<const short8*>(Bp + q * 512 + loff);             \
        short8 fb1 = *reinterpret_cast<const short8*>(Bp + 8192 + q * 512 + loff);      \
        a00 = __builtin_amdgcn_mfma_f32_32x32x16_bf16(fa0, fb0, a00, 0, 0, 0);          \
        a01 = __builtin_amdgcn_mfma_f32_32x32x16_bf16(fa0, fb1, a01, 0, 0, 0);          \
        a10 = __builtin_amdgcn_mfma_f32_32x32x16_bf16(fa1, fb0, a10, 0, 0, 0);          \
        a11 = __builtin_amdgcn_mfma_f32_32x32x16_bf16(fa1, fb1, a11, 0, 0, 0);          \
    }
    Ap = zhF + Aoff; Bp = ehF + Boff; QLOOP          // seg 0: zh*eh
    Ap = zlF + Aoff;                  QLOOP          // seg 1: zl*eh
    Ap = zhF + Aoff; Bp = elF + Boff; QLOOP          // seg 2: zh*el
#undef QLOOP

    // epilogue: per n-row, (min1, idx, min2) over this wave's 64 k
    const float esqA = esq[kw + lr];
    const float esqB = esq[kw + 32 + lr];
#pragma unroll
    for (int i = 0; i < 2; ++i) {
        const f32x16 accA = i ? a10 : a00;
        const f32x16 accB = i ? a11 : a01;
#pragma unroll
        for (int r = 0; r < 16; ++r) {
            const int nl = i * 32 + (r & 3) + 8 * (r >> 2) + 4 * lh;
            const float xs = xsq[n0 + nl];
            float sA = (xs + esqA) - 2.0f * accA[r];
            float sB = (xs + esqB) - 2.0f * accB[r];
            float m1 = sA, m2 = sB; int i1 = kw + lr;
            if (sB < sA) { m1 = sB; m2 = sA; i1 = kw + 32 + lr; }
#pragma unroll
            for (int off = 16; off >= 1; off >>= 1) {
                float om1 = __shfl_xor(m1, off, 64);
                float om2 = __shfl_xor(m2, off, 64);
                int   oi  = __shfl_xor(i1, off, 64);
                if (om1 < m1)      { m2 = fminf(m1, om2); m1 = om1; i1 = oi; }
                else if (om1 > m1) { m2 = fminf(m2, om1); }
                else               { m2 = m1; i1 = min(i1, oi); }
            }
            if (lr == 0) { lm1[w][nl] = m1; lm2[w][nl] = m2; li1[w][nl] = i1; }
        }
    }
    __syncthreads();
    if (tid < 64) {
        float m1 = lm1[0][tid], m2 = lm2[0][tid];
        int i1 = li1[0][tid];
#pragma unroll
        for (int ww = 1; ww < 4; ++ww) {
            float q1 = lm1[ww][tid], q2 = lm2[ww][tid];
            int qi = li1[ww][tid];
            if (q1 < m1)      { m2 = fminf(m1, q2); m1 = q1; i1 = qi; }
            else if (q1 > m1) { m2 = fminf(m2, q1); }
            else              { m2 = m1; }   // ww ascending k: keep lower idx
        }
        size_t p = (size_t)kb * N_VEC + n0 + tid;
        pm1[p] = m1; pm2[p] = m2; pix[p] = (unsigned short)i1;
    }
}

__global__ __launch_bounds__(256) void merge_kernel(
    const float* __restrict__ pm1, const float* __restrict__ pm2,
    const unsigned short* __restrict__ pix,
    int* __restrict__ screen_idx, unsigned* __restrict__ flag_list,
    unsigned* __restrict__ flag_count) {
    int n = blockIdx.x * 256 + threadIdx.x;
    float m1 = 3.4e38f, m2 = 3.4e38f;
    int i1 = 0;
    for (int kb = 0; kb < 4; ++kb) {
        size_t p = (size_t)kb * N_VEC + n;
        float a1 = pm1[p], a2 = pm2[p];
        int ai = (int)pix[p];
        if (a1 < m1)      { m2 = fminf(m1, a2); m1 = a1; i1 = ai; }
        else if (a1 > m1) { m2 = fminf(m2, a1); }
        else              { m2 = m1; i1 = min(i1, ai); }
    }
    if (m2 - m1 <= T_GAP) {
        screen_idx[n] = -1;
        unsigned pos = atomicAdd(flag_count, 1u);
        flag_list[pos] = (unsigned)n;
    } else {
        screen_idx[n] = i1;
    }
}

// ---------- exact-chain refine of flagged rows (8 rows/group) ----------

__global__ __launch_bounds__(256) void refine_kernel(
    const float* __restrict__ z, const float* __restrict__ embT,
    const float* __restrict__ esq, const float* __restrict__ xsq,
    const unsigned* __restrict__ flag_list, const unsigned* __restrict__ flag_count,
    float* __restrict__ out_idx, unsigned* __restrict__ counts) {
#pragma clang fp contract(off)
    __shared__ float zrow[8][256];
    __shared__ int nrow[8];
    __shared__ unsigned long long red[8][4];
    const int tid = threadIdx.x;
    const unsigned cnt = *flag_count;
    const unsigned groups = (cnt + 7) >> 3;
    const int kbase = tid * 4;
    for (unsigned g = blockIdx.x; g < groups; g += gridDim.x) {
        __syncthreads();
        if (tid < 8) nrow[tid] = (g * 8 + tid < cnt) ? (int)flag_list[g * 8 + tid] : -1;
        __syncthreads();
        for (int r = 0; r < 8; ++r) {
            int n = nrow[r];
            if (n >= 0) {
                int b = n >> 14, s = n & 16383;
                zrow[r][tid] = z[((size_t)b << 22) + ((size_t)tid << 14) + s];
            }
        }
        __syncthreads();
        float acc[8][4];
#pragma unroll
        for (int r = 0; r < 8; ++r)
#pragma unroll
            for (int j = 0; j < 4; ++j) acc[r][j] = 0.0f;
        for (int c4 = 0; c4 < 64; ++c4) {
            float4 ek[4];
#pragma unroll
            for (int x = 0; x < 4; ++x)
                ek[x] = *reinterpret_cast<const float4*>(embT + (size_t)(c4 * 4 + x) * K_CODES + kbase);
#pragma unroll
            for (int r = 0; r < 8; ++r) {
                float4 zv = *reinterpret_cast<const float4*>(&zrow[r][c4 * 4]);
                float a;
                a = acc[r][0];
                a = fmaf(zv.x, ek[0].x, a); a = fmaf(zv.y, ek[1].x, a);
                a = fmaf(zv.z, ek[2].x, a); a = fmaf(zv.w, ek[3].x, a);
                acc[r][0] = a;
                a = acc[r][1];
                a = fmaf(zv.x, ek[0].y, a); a = fmaf(zv.y, ek[1].y, a);
                a = fmaf(zv.z, ek[2].y, a); a = fmaf(zv.w, ek[3].y, a);
                acc[r][1] = a;
                a = acc[r][2];
                a = fmaf(zv.x, ek[0].z, a); a = fmaf(zv.y, ek[1].z, a);
                a = fmaf(zv.z, ek[2].z, a); a = fmaf(zv.w, ek[3].z, a);
                acc[r][2] = a;
                a = acc[r][3];
                a = fmaf(zv.x, ek[0].w, a); a = fmaf(zv.y, ek[1].w, a);
                a = fmaf(zv.z, ek[2].w, a); a = fmaf(zv.w, ek[3].w, a);
                acc[r][3] = a;
            }
        }
        float esql[4];
#pragma unroll
        for (int j = 0; j < 4; ++j) esql[j] = esq[kbase + j];
#pragma unroll
        for (int r = 0; r < 8; ++r) {
            int n = nrow[r];
            float xs = (n >= 0) ? xsq[n] : 0.0f;
            float m = 3.4e38f;
            int mi = 0;
#pragma unroll
            for (int j = 0; j < 4; ++j) {
                float t1 = xs + esql[j];
                float d = t1 - 2.0f * acc[r][j];
                if (d < m) { m = d; mi = kbase + j; }
            }
            unsigned long long p = ((unsigned long long)__float_as_uint(m) << 32) | (unsigned)mi;
            for (int off = 32; off >= 1; off >>= 1) {
                unsigned long long o = __shfl_xor(p, off, 64);
                p = (o < p) ? o : p;
            }
            if ((tid & 63) == 0) red[r][tid >> 6] = p;
        }
        __syncthreads();
        if (tid < 8 && nrow[tid] >= 0) {
            unsigned long long p = red[tid][0];
#pragma unroll
            for (int ww = 1; ww < 4; ++ww) { unsigned long long o = red[tid][ww]; p = (o < p) ? o : p; }
            int idx = (int)(p & 0xFFFFFFFFull);
            out_idx[nrow[tid]] = (float)idx;
            atomicAdd(&counts[idx], 1u);
        }
    }
}

__global__ __launch_bounds__(256) void emit_kernel(const int* __restrict__ screen_idx,
                                                   float* __restrict__ out_idx,
                                                   unsigned* __restrict__ counts) {
    int n = blockIdx.x * 256 + threadIdx.x;
    int iv = screen_idx[n];
    if (iv >= 0) {
        out_idx[n] = (float)iv;
        atomicAdd(&counts[iv], 1u);
    }
}

// ---------- gather + losses (validated) ----------

__global__ __launch_bounds__(256) void gather_kernel(
    const float* __restrict__ z, const float* __restrict__ embT,
    const float* __restrict__ out_idx, float* __restrict__ out,
    double* __restrict__ loss_acc) {
    const int tid = threadIdx.x;
    const int ct = blockIdx.x & 3;
    const int st = (blockIdx.x >> 2) & 15;
    const int b  = blockIdx.x >> 6;
    const int s0 = st * 1024;
    const int c0 = ct * 64;

    int idx[4];
#pragma unroll
    for (int q = 0; q < 4; ++q)
        idx[q] = (int)out_idx[(b << 14) + s0 + 4 * tid + q];

    const float* zb = z + ((size_t)b << 22) + s0 + 4 * tid;
    float* ob = out + ((size_t)b << 22) + s0 + 4 * tid;

    double local = 0.0;
    for (int c = 0; c < 64; ++c) {
        const int cg = c0 + c;
        const float* er = embT + (size_t)cg * K_CODES;
        float4 zv = *reinterpret_cast<const float4*>(zb + ((size_t)cg << 14));
        float4 ov;
        float d0 = er[idx[0]] - zv.x;
        float d1 = er[idx[1]] - zv.y;
        float d2 = er[idx[2]] - zv.z;
        float d3 = er[idx[3]] - zv.w;
        ov.x = zv.x + d0; ov.y = zv.y + d1; ov.z = zv.z + d2; ov.w = zv.w + d3;
        *reinterpret_cast<float4*>(ob + ((size_t)cg << 14)) = ov;
        local += (double)d0 * d0 + (double)d1 * d1 + (double)d2 * d2 + (double)d3 * d3;
    }
    for (int off = 32; off >= 1; off >>= 1) local += __shfl_down(local, off, 64);
    __shared__ double redd[4];
    if ((tid & 63) == 0) redd[tid >> 6] = local;
    __syncthreads();
    if (tid == 0) atomicAdd(loss_acc, redd[0] + redd[1] + redd[2] + redd[3]);
}

__global__ void finalize_kernel(const unsigned* __restrict__ counts,
                                const double* __restrict__ loss_acc,
                                float* __restrict__ out) {
    int tid = threadIdx.x;
    double s = 0.0;
    for (int k = tid; k < K_CODES; k += 256) {
        float avg = (float)counts[k] / 65536.0f;
        float t = avg * logf(avg + 1e-10f);
        s += (double)t;
    }
    for (int off = 32; off >= 1; off >>= 1) s += __shfl_down(s, off, 64);
    __shared__ double red[4];
    if ((tid & 63) == 0) red[tid >> 6] = s;
    __syncthreads();
    if (tid == 0) {
        double tot = red[0] + red[1] + red[2] + red[3];
        out[OUT_PP_OFF]   = expf((float)(-tot));
        out[OUT_LOSS_OFF] = 1.25f * (float)(loss_acc[0] / 16777216.0);
    }
}

extern "C" void kernel_launch(void* const* d_in, const int* in_sizes, int n_in,
                              void* d_out, int out_size, void* d_ws, size_t ws_size,
                              hipStream_t stream) {
    const float* z   = (const float*)d_in[0];
    const float* emb = (const float*)d_in[1];
    float* out = (float*)d_out;
    char* ws = (char*)d_ws;

    unsigned short* ehF = (unsigned short*)(ws + WS_EH);
    unsigned short* elF = (unsigned short*)(ws + WS_EL);
    float*    esq       = (float*)(ws + WS_ESQ);
    float*    xsq       = (float*)(ws + WS_XSQ);
    unsigned* counts    = (unsigned*)(ws + WS_CNT);
    double*   loss_acc  = (double*)(ws + WS_LOSS);
    unsigned* flag_cnt  = (unsigned*)(ws + WS_FLC);
    int*      sidx      = (int*)(ws + WS_SIDX);
    unsigned* flist     = (unsigned*)(ws + WS_FLIST);
    float*    pm1       = (float*)(ws + WS_PM1);
    float*    pm2       = (float*)(ws + WS_PM2);
    unsigned short* pix = (unsigned short*)(ws + WS_PIX);
    float*    embT      = (float*)(ws + WS_EMBT);

    unsigned short* zhF = (unsigned short*)out;                // [0, 33.5 MB)
    unsigned short* zlF = (unsigned short*)(out + 8388608);    // [33.5, 67 MB)
    float* out_idx = out + OUT_IDX_OFF;

    hipMemsetAsync(ws + WS_CNT, 0, 4108, stream);   // counts + loss + flag_count

    convert_z_kernel<<<1024, 256, 0, stream>>>(z, zhF, zlF);
    convert_e_kernel<<<128, 256, 0, stream>>>(emb, ehF, elF);
    esq_kernel<<<K_CODES / 64, 256, 0, stream>>>(emb, esq);
    xsq_kernel<<<N_VEC / 256, 256, 0, stream>>>(z, xsq);
    screen_kernel<<<4096, 256, 0, stream>>>(zhF, zlF, ehF, elF, esq, xsq, pm1, pm2, pix);
    merge_kernel<<<256, 256, 0, stream>>>(pm1, pm2, pix, sidx, flist, flag_cnt);
    transpose_kernel<<<dim3(16, 4), 256, 0, stream>>>(emb, embT);   // embT overlays pm1
    refine_kernel<<<1024, 256, 0, stream>>>(z, embT, esq, xsq, flist, flag_cnt, out_idx, counts);
    emit_kernel<<<256, 256, 0, stream>>>(sidx, out_idx, counts);
    gather_kernel<<<256, 256, 0, stream>>>(z, embT, out_idx, out, loss_acc);
    finalize_kernel<<<1, 256, 0, stream>>>(counts, loss_acc, out);
}

// Round 8
// 341.811 us; speedup vs baseline: 2.4509x; 2.4509x over previous
//
#include <hip/hip_runtime.h>

// VQ-VAE vector quantizer, MI355X — MFMA screen (fragment-major + LDS-staged) + exact refine.
// z: (4,256,16,32,32) f32 ; emb: (1024,256) f32
// out (f32): z_q_st[16777216] | vq_loss | perplexity | indices[65536]
//
// Exactness contract (validated rounds 2-7, absmax 0):
//   x_sq[n], e_sq[k]: numpy pairwise sum of fl32(v*v) (two 128-blocks, 8 accs)
//   xe[n][k]: single sequential f32 FMA chain over c=0..255
//   d = fl32( fl32(x_sq+e_sq) - 2*xe ), argmin first-min tie-break.
// Screen = bf16-split MFMA (zh*eh + zl*eh + zh*el, 32x32x16; per-acc accumulation
// order identical to rounds 6-7); merged rows with gap <= T=4e-4 go to exact
// scalar-chain refine. Screen error only increases flag rate, never wrongness.
//
// Round-8: round 7 (no-LDS global-direct) thrashed L2 (2 GB requests, 93% miss,
// 1.83 GB HBM traffic, MfmaUtil 6%). Recombine: fragment-major layout lets LDS
// staging be a VERBATIM 1 KB-chunk copy -> lane-linear ds_read_b128, zero bank
// conflicts (round 6's killer), while restoring block-level reuse (round 6's
// 95% L2 hit). Block 128n x 256k, wave 64n x 128k (2x4 acc = 768 B LDS/MFMA),
// double-buffered reg-staging (issue-early/write-late), 1 barrier/step.

#define C_DIM 256
#define K_CODES 1024
#define N_VEC 65536
#define T_GAP 4e-4f

#define OUT_ZQ_SIZE 16777216
#define OUT_LOSS_OFF 16777216
#define OUT_PP_OFF   16777217
#define OUT_IDX_OFF  16777218

// ws layout (bytes)
#define WS_EH    0          // bf16 frag-major [32 kt][16 q][64 l][8]   512 KB
#define WS_EL    524288     // same                                     512 KB
#define WS_ESQ   1048576    // f32 [1024]
#define WS_XSQ   1052672    // f32 [65536]
#define WS_CNT   1314816    // u32 counts[1024]
#define WS_LOSS  1318912    // f64 loss
#define WS_FLC   1318920    // u32 flag count
#define WS_SIDX  1318928    // i32 screen_idx[65536]
#define WS_FLIST 1581072    // u32 flag_list[65536]
#define WS_PM1   1843264    // f32 [4][65536]
#define WS_EMBT  1843264    // f32 [256][1024] (overlays PM1 after merge)
#define WS_PM2   2891840    // f32 [4][65536]
#define WS_PIX   3940416    // u16 [4][65536]  (ends 4464704)

typedef __attribute__((ext_vector_type(8))) short short8;
typedef __attribute__((ext_vector_type(8))) unsigned short ushort8;
typedef __attribute__((ext_vector_type(16))) float f32x16;

__device__ __forceinline__ unsigned short bf16_rne(float v) {
    unsigned u = __float_as_uint(v);
    unsigned r = (u + 0x7FFFu + ((u >> 16) & 1u)) >> 16;
    return (unsigned short)r;
}

// fragment-major address (in shorts) of element (row, c) within a panel:
//   tile = row>>5, q = c>>4, lane = (row&31) + 32*((c>>3)&1), j = c&7
//   off  = tile*8192 + q*512 + lane*8 + j

// ---------- conversions ----------

__global__ __launch_bounds__(256) void convert_z_kernel(const float* __restrict__ z,
                                                        unsigned short* __restrict__ zhF,
                                                        unsigned short* __restrict__ zlF) {
    const int tid = threadIdx.x;
    const int ln = tid & 63;
    const int og = tid >> 6;
    const int n0 = blockIdx.x * 64;
    const int b = n0 >> 14, s0 = n0 & 16383;
    const int n = n0 + ln;
    const size_t zbase = ((size_t)b << 22) + s0 + ln;
    const size_t tbase = (size_t)(n >> 5) * 8192;
    const int lr = n & 31;
#pragma unroll
    for (int t = 0; t < 8; ++t) {
        int o = og + t * 4;        // c-octet 0..31
        int c0 = o * 8;
        ushort8 hb, lb;
#pragma unroll
        for (int j = 0; j < 8; ++j) {
            float v = z[zbase + ((size_t)(c0 + j) << 14)];
            unsigned short h = bf16_rne(v);
            hb[j] = h;
            lb[j] = bf16_rne(v - __uint_as_float((unsigned)h << 16));
        }
        size_t off = tbase + (size_t)(o >> 1) * 512 + (size_t)(lr + 32 * (o & 1)) * 8;
        *reinterpret_cast<ushort8*>(zhF + off) = hb;
        *reinterpret_cast<ushort8*>(zlF + off) = lb;
    }
}

__global__ __launch_bounds__(256) void convert_e_kernel(const float* __restrict__ emb,
                                                        unsigned short* __restrict__ ehF,
                                                        unsigned short* __restrict__ elF) {
    int t = blockIdx.x * 256 + threadIdx.x;   // 32768 threads
    int k = t >> 5, o = t & 31;
    int c0 = o * 8;
    ushort8 hb, lb;
#pragma unroll
    for (int j = 0; j < 8; ++j) {
        float v = emb[k * C_DIM + c0 + j];
        unsigned short h = bf16_rne(v);
        hb[j] = h;
        lb[j] = bf16_rne(v - __uint_as_float((unsigned)h << 16));
    }
    size_t off = (size_t)(k >> 5) * 8192 + (size_t)(o >> 1) * 512 + (size_t)((k & 31) + 32 * (o & 1)) * 8;
    *reinterpret_cast<ushort8*>(ehF + off) = hb;
    *reinterpret_cast<ushort8*>(elF + off) = lb;
}

// ---------- exact norms (validated) ----------

__device__ __forceinline__ float pairwise_sq_128(const float* p) {
#pragma clang fp contract(off)
    float r[8];
#pragma unroll
    for (int j = 0; j < 8; ++j) { float v = p[j]; r[j] = v * v; }
#pragma unroll
    for (int i = 8; i < 128; i += 8)
#pragma unroll
        for (int j = 0; j < 8; ++j) { float v = p[i + j]; float t = v * v; r[j] = r[j] + t; }
    return ((r[0] + r[1]) + (r[2] + r[3])) + ((r[4] + r[5]) + (r[6] + r[7]));
}

__global__ __launch_bounds__(256) void esq_kernel(const float* __restrict__ emb,
                                                  float* __restrict__ esq) {
#pragma clang fp contract(off)
    __shared__ float tile[64 * 260];
    const int tid = threadIdx.x;
    const int k0 = blockIdx.x * 64;
#pragma unroll
    for (int r = 0; r < 64; ++r) {
        int idx = r * 256 + tid;
        tile[(idx >> 8) * 260 + (idx & 255)] = emb[k0 * C_DIM + idx];
    }
    __syncthreads();
    if (tid < 64) {
        const float* row = &tile[tid * 260];
        esq[k0 + tid] = pairwise_sq_128(row) + pairwise_sq_128(row + 128);
    }
}

__global__ __launch_bounds__(256) void xsq_kernel(const float* __restrict__ z,
                                                  float* __restrict__ xsq) {
#pragma clang fp contract(off)
    const int n = blockIdx.x * 256 + threadIdx.x;
    const int b = n >> 14, s = n & 16383;
    const float* base = z + ((size_t)b << 22) + s;
    float r[8], res;
#pragma unroll
    for (int j = 0; j < 8; ++j) { float v = base[(size_t)j << 14]; r[j] = v * v; }
#pragma unroll
    for (int i = 8; i < 128; i += 8)
#pragma unroll
        for (int j = 0; j < 8; ++j) { float v = base[(size_t)(i + j) << 14]; float t = v * v; r[j] = r[j] + t; }
    res = ((r[0] + r[1]) + (r[2] + r[3])) + ((r[4] + r[5]) + (r[6] + r[7]));
#pragma unroll
    for (int j = 0; j < 8; ++j) { float v = base[(size_t)(128 + j) << 14]; r[j] = v * v; }
#pragma unroll
    for (int i = 136; i < 256; i += 8)
#pragma unroll
        for (int j = 0; j < 8; ++j) { float v = base[(size_t)(i + j) << 14]; float t = v * v; r[j] = r[j] + t; }
    res = res + (((r[0] + r[1]) + (r[2] + r[3])) + ((r[4] + r[5]) + (r[6] + r[7])));
    xsq[n] = res;
}

__global__ __launch_bounds__(256) void transpose_kernel(const float* __restrict__ emb,
                                                        float* __restrict__ embT) {
    __shared__ float t[64][65];
    const int k0 = blockIdx.x * 64;
    const int c0 = blockIdx.y * 64;
    const int tx = threadIdx.x & 63, ty = threadIdx.x >> 6;
    for (int r = ty; r < 64; r += 4)
        t[r][tx] = emb[(k0 + r) * C_DIM + c0 + tx];
    __syncthreads();
    for (int r = ty; r < 64; r += 4)
        embT[(c0 + r) * K_CODES + k0 + tx] = t[tx][r];
}

// ---------- MFMA screen: frag-major LDS-staged; block 128n x 256k, wave 64n x 128k ----------

__global__ __launch_bounds__(256, 2) void screen_kernel(
    const unsigned short* __restrict__ zhF, const unsigned short* __restrict__ zlF,
    const unsigned short* __restrict__ ehF, const unsigned short* __restrict__ elF,
    const float* __restrict__ esq, const float* __restrict__ xsq,
    float* __restrict__ pm1, float* __restrict__ pm2,
    unsigned short* __restrict__ pix) {
    __shared__ __align__(16) short lbuf[2][12 * 512];   // 24 KB: chunks 0-3 = A tiles, 4-11 = B tiles
    __shared__ float lm1[2][128], lm2[2][128];
    __shared__ int   li1[2][128];

    const int tid = threadIdx.x;
    const int w = tid >> 6, l = tid & 63, lr = l & 31, lh = l >> 5;
    const int wn = w >> 1, wk = w & 1;
    const int bid = blockIdx.x;
    const int v = (bid & 7) * 256 + (bid >> 3);   // XCD-chunked bijective swizzle (2048 = 8*256)
    const int nb = v >> 2, kb = v & 3;
    const int n0 = nb * 128;
    const int k0 = kb * 256;
    const size_t atile0 = (size_t)(nb * 4) * 8192;   // shorts
    const size_t btile0 = (size_t)(kb * 8) * 8192;
    const int loff = l * 8;

    f32x16 acc[2][4];
#pragma unroll
    for (int i = 0; i < 2; ++i)
#pragma unroll
        for (int j = 0; j < 4; ++j)
#pragma unroll
            for (int r = 0; r < 16; ++r) acc[i][j][r] = 0.0f;

    // this wave stages chunks 3w .. 3w+2 each step
    short8 st[3];

    // prologue: stage step 0 (seg 0, q 0)
#pragma unroll
    for (int ci = 0; ci < 3; ++ci) {
        int c = 3 * w + ci;
        const unsigned short* p = (c < 4)
            ? zhF + atile0 + (size_t)c * 8192 + loff
            : ehF + btile0 + (size_t)(c - 4) * 8192 + loff;
        st[ci] = *reinterpret_cast<const short8*>(p);
    }
#pragma unroll
    for (int ci = 0; ci < 3; ++ci)
        *reinterpret_cast<short8*>(&lbuf[0][(3 * w + ci) * 512 + loff]) = st[ci];
    __syncthreads();

    for (int s = 0; s < 48; ++s) {
        const int cur = s & 1;
        const bool more = (s + 1) < 48;
        if (more) {   // issue next step's loads early (latency hides under MFMAs)
            const int s1 = s + 1, seg1 = s1 >> 4, q1 = s1 & 15;
            const unsigned short* As = (seg1 == 1) ? zlF : zhF;
            const unsigned short* Bs = (seg1 == 2) ? elF : ehF;
#pragma unroll
            for (int ci = 0; ci < 3; ++ci) {
                int c = 3 * w + ci;
                const unsigned short* p = (c < 4)
                    ? As + atile0 + (size_t)c * 8192 + (size_t)q1 * 512 + loff
                    : Bs + btile0 + (size_t)(c - 4) * 8192 + (size_t)q1 * 512 + loff;
                st[ci] = *reinterpret_cast<const short8*>(p);
            }
        }
        // compute step s: lane-linear frag reads (conflict-free), 8 MFMAs
        short8 fa[2], fb[4];
#pragma unroll
        for (int i = 0; i < 2; ++i)
            fa[i] = *reinterpret_cast<const short8*>(&lbuf[cur][(wn * 2 + i) * 512 + loff]);
#pragma unroll
        for (int j = 0; j < 4; ++j)
            fb[j] = *reinterpret_cast<const short8*>(&lbuf[cur][(4 + wk * 4 + j) * 512 + loff]);
#pragma unroll
        for (int i = 0; i < 2; ++i)
#pragma unroll
            for (int j = 0; j < 4; ++j)
                acc[i][j] = __builtin_amdgcn_mfma_f32_32x32x16_bf16(fa[i], fb[j], acc[i][j], 0, 0, 0);
        if (more) {
#pragma unroll
            for (int ci = 0; ci < 3; ++ci)
                *reinterpret_cast<short8*>(&lbuf[cur ^ 1][(3 * w + ci) * 512 + loff]) = st[ci];
        }
        __syncthreads();
    }

    // epilogue: per n-row (min1, idx, min2) over this wave's 128 k, then merge wk halves
    float esql[4];
#pragma unroll
    for (int j = 0; j < 4; ++j) esql[j] = esq[k0 + wk * 128 + j * 32 + lr];
#pragma unroll
    for (int i = 0; i < 2; ++i) {
#pragma unroll
        for (int r = 0; r < 16; ++r) {
            const int nl = (wn * 2 + i) * 32 + (r & 3) + 8 * (r >> 2) + 4 * lh;
            const float xs = xsq[n0 + nl];
            float m1 = 3.4e38f, m2 = 3.4e38f;
            int i1 = 0;
#pragma unroll
            for (int j = 0; j < 4; ++j) {
                float sv = (xs + esql[j]) - 2.0f * acc[i][j][r];
                int kg = k0 + wk * 128 + j * 32 + lr;
                if (sv < m1) { m2 = m1; m1 = sv; i1 = kg; }
                else m2 = fminf(m2, sv);
            }
#pragma unroll
            for (int off = 16; off >= 1; off >>= 1) {
                float om1 = __shfl_xor(m1, off, 64);
                float om2 = __shfl_xor(m2, off, 64);
                int   oi  = __shfl_xor(i1, off, 64);
                if (om1 < m1)      { m2 = fminf(m1, om2); m1 = om1; i1 = oi; }
                else if (om1 > m1) { m2 = fminf(m2, om1); }
                else               { m2 = m1; i1 = min(i1, oi); }
            }
            if (lr == 0) { lm1[wk][nl] = m1; lm2[wk][nl] = m2; li1[wk][nl] = i1; }
        }
    }
    __syncthreads();
    if (tid < 128) {
        float m1 = lm1[0][tid], m2 = lm2[0][tid];
        int i1 = li1[0][tid];
        float q1 = lm1[1][tid], q2 = lm2[1][tid];
        int qi = li1[1][tid];
        if (q1 < m1)      { m2 = fminf(m1, q2); m1 = q1; i1 = qi; }
        else if (q1 > m1) { m2 = fminf(m2, q1); }
        else              { m2 = m1; }   // wk ascending k: keep lower idx
        size_t p = (size_t)kb * N_VEC + n0 + tid;
        pm1[p] = m1; pm2[p] = m2; pix[p] = (unsigned short)i1;
    }
}

__global__ __launch_bounds__(256) void merge_kernel(
    const float* __restrict__ pm1, const float* __restrict__ pm2,
    const unsigned short* __restrict__ pix,
    int* __restrict__ screen_idx, unsigned* __restrict__ flag_list,
    unsigned* __restrict__ flag_count) {
    int n = blockIdx.x * 256 + threadIdx.x;
    float m1 = 3.4e38f, m2 = 3.4e38f;
    int i1 = 0;
    for (int kb = 0; kb < 4; ++kb) {
        size_t p = (size_t)kb * N_VEC + n;
        float a1 = pm1[p], a2 = pm2[p];
        int ai = (int)pix[p];
        if (a1 < m1)      { m2 = fminf(m1, a2); m1 = a1; i1 = ai; }
        else if (a1 > m1) { m2 = fminf(m2, a1); }
        else              { m2 = m1; i1 = min(i1, ai); }
    }
    if (m2 - m1 <= T_GAP) {
        screen_idx[n] = -1;
        unsigned pos = atomicAdd(flag_count, 1u);
        flag_list[pos] = (unsigned)n;
    } else {
        screen_idx[n] = i1;
    }
}

// ---------- exact-chain refine of flagged rows (8 rows/group) ----------

__global__ __launch_bounds__(256) void refine_kernel(
    const float* __restrict__ z, const float* __restrict__ embT,
    const float* __restrict__ esq, const float* __restrict__ xsq,
    const unsigned* __restrict__ flag_list, const unsigned* __restrict__ flag_count,
    float* __restrict__ out_idx, unsigned* __restrict__ counts) {
#pragma clang fp contract(off)
    __shared__ float zrow[8][256];
    __shared__ int nrow[8];
    __shared__ unsigned long long red[8][4];
    const int tid = threadIdx.x;
    const unsigned cnt = *flag_count;
    const unsigned groups = (cnt + 7) >> 3;
    const int kbase = tid * 4;
    for (unsigned g = blockIdx.x; g < groups; g += gridDim.x) {
        __syncthreads();
        if (tid < 8) nrow[tid] = (g * 8 + tid < cnt) ? (int)flag_list[g * 8 + tid] : -1;
        __syncthreads();
        for (int r = 0; r < 8; ++r) {
            int n = nrow[r];
            if (n >= 0) {
                int b = n >> 14, s = n & 16383;
                zrow[r][tid] = z[((size_t)b << 22) + ((size_t)tid << 14) + s];
            }
        }
        __syncthreads();
        float acc[8][4];
#pragma unroll
        for (int r = 0; r < 8; ++r)
#pragma unroll
            for (int j = 0; j < 4; ++j) acc[r][j] = 0.0f;
        for (int c4 = 0; c4 < 64; ++c4) {
            float4 ek[4];
#pragma unroll
            for (int x = 0; x < 4; ++x)
                ek[x] = *reinterpret_cast<const float4*>(embT + (size_t)(c4 * 4 + x) * K_CODES + kbase);
#pragma unroll
            for (int r = 0; r < 8; ++r) {
                float4 zv = *reinterpret_cast<const float4*>(&zrow[r][c4 * 4]);
                float a;
                a = acc[r][0];
                a = fmaf(zv.x, ek[0].x, a); a = fmaf(zv.y, ek[1].x, a);
                a = fmaf(zv.z, ek[2].x, a); a = fmaf(zv.w, ek[3].x, a);
                acc[r][0] = a;
                a = acc[r][1];
                a = fmaf(zv.x, ek[0].y, a); a = fmaf(zv.y, ek[1].y, a);
                a = fmaf(zv.z, ek[2].y, a); a = fmaf(zv.w, ek[3].y, a);
                acc[r][1] = a;
                a = acc[r][2];
                a = fmaf(zv.x, ek[0].z, a); a = fmaf(zv.y, ek[1].z, a);
                a = fmaf(zv.z, ek[2].z, a); a = fmaf(zv.w, ek[3].z, a);
                acc[r][2] = a;
                a = acc[r][3];
                a = fmaf(zv.x, ek[0].w, a); a = fmaf(zv.y, ek[1].w, a);
                a = fmaf(zv.z, ek[2].w, a); a = fmaf(zv.w, ek[3].w, a);
                acc[r][3] = a;
            }
        }
        float esql[4];
#pragma unroll
        for (int j = 0; j < 4; ++j) esql[j] = esq[kbase + j];
#pragma unroll
        for (int r = 0; r < 8; ++r) {
            int n = nrow[r];
            float xs = (n >= 0) ? xsq[n] : 0.0f;
            float m = 3.4e38f;
            int mi = 0;
#pragma unroll
            for (int j = 0; j < 4; ++j) {
                float t1 = xs + esql[j];
                float d = t1 - 2.0f * acc[r][j];
                if (d < m) { m = d; mi = kbase + j; }
            }
            unsigned long long p = ((unsigned long long)__float_as_uint(m) << 32) | (unsigned)mi;
            for (int off = 32; off >= 1; off >>= 1) {
                unsigned long long o = __shfl_xor(p, off, 64);
                p = (o < p) ? o : p;
            }
            if ((tid & 63) == 0) red[r][tid >> 6] = p;
        }
        __syncthreads();
        if (tid < 8 && nrow[tid] >= 0) {
            unsigned long long p = red[tid][0];
#pragma unroll
            for (int ww = 1; ww < 4; ++ww) { unsigned long long o = red[tid][ww]; p = (o < p) ? o : p; }
            int idx = (int)(p & 0xFFFFFFFFull);
            out_idx[nrow[tid]] = (float)idx;
            atomicAdd(&counts[idx], 1u);
        }
    }
}

__global__ __launch_bounds__(256) void emit_kernel(const int* __restrict__ screen_idx,
                                                   float* __restrict__ out_idx,
                                                   unsigned* __restrict__ counts) {
    int n = blockIdx.x * 256 + threadIdx.x;
    int iv = screen_idx[n];
    if (iv >= 0) {
        out_idx[n] = (float)iv;
        atomicAdd(&counts[iv], 1u);
    }
}

// ---------- gather + losses (validated) ----------

__global__ __launch_bounds__(256) void gather_kernel(
    const float* __restrict__ z, const float* __restrict__ embT,
    const float* __restrict__ out_idx, float* __restrict__ out,
    double* __restrict__ loss_acc) {
    const int tid = threadIdx.x;
    const int ct = blockIdx.x & 3;
    const int st = (blockIdx.x >> 2) & 15;
    const int b  = blockIdx.x >> 6;
    const int s0 = st * 1024;
    const int c0 = ct * 64;

    int idx[4];
#pragma unroll
    for (int q = 0; q < 4; ++q)
        idx[q] = (int)out_idx[(b << 14) + s0 + 4 * tid + q];

    const float* zb = z + ((size_t)b << 22) + s0 + 4 * tid;
    float* ob = out + ((size_t)b << 22) + s0 + 4 * tid;

    double local = 0.0;
    for (int c = 0; c < 64; ++c) {
        const int cg = c0 + c;
        const float* er = embT + (size_t)cg * K_CODES;
        float4 zv = *reinterpret_cast<const float4*>(zb + ((size_t)cg << 14));
        float4 ov;
        float d0 = er[idx[0]] - zv.x;
        float d1 = er[idx[1]] - zv.y;
        float d2 = er[idx[2]] - zv.z;
        float d3 = er[idx[3]] - zv.w;
        ov.x = zv.x + d0; ov.y = zv.y + d1; ov.z = zv.z + d2; ov.w = zv.w + d3;
        *reinterpret_cast<float4*>(ob + ((size_t)cg << 14)) = ov;
        local += (double)d0 * d0 + (double)d1 * d1 + (double)d2 * d2 + (double)d3 * d3;
    }
    for (int off = 32; off >= 1; off >>= 1) local += __shfl_down(local, off, 64);
    __shared__ double redd[4];
    if ((tid & 63) == 0) redd[tid >> 6] = local;
    __syncthreads();
    if (tid == 0) atomicAdd(loss_acc, redd[0] + redd[1] + redd[2] + redd[3]);
}

__global__ void finalize_kernel(const unsigned* __restrict__ counts,
                                const double* __restrict__ loss_acc,
                                float* __restrict__ out) {
    int tid = threadIdx.x;
    double s = 0.0;
    for (int k = tid; k < K_CODES; k += 256) {
        float avg = (float)counts[k] / 65536.0f;
        float t = avg * logf(avg + 1e-10f);
        s += (double)t;
    }
    for (int off = 32; off >= 1; off >>= 1) s += __shfl_down(s, off, 64);
    __shared__ double red[4];
    if ((tid & 63) == 0) red[tid >> 6] = s;
    __syncthreads();
    if (tid == 0) {
        double tot = red[0] + red[1] + red[2] + red[3];
        out[OUT_PP_OFF]   = expf((float)(-tot));
        out[OUT_LOSS_OFF] = 1.25f * (float)(loss_acc[0] / 16777216.0);
    }
}

extern "C" void kernel_launch(void* const* d_in, const int* in_sizes, int n_in,
                              void* d_out, int out_size, void* d_ws, size_t ws_size,
                              hipStream_t stream) {
    const float* z   = (const float*)d_in[0];
    const float* emb = (const float*)d_in[1];
    float* out = (float*)d_out;
    char* ws = (char*)d_ws;

    unsigned short* ehF = (unsigned short*)(ws + WS_EH);
    unsigned short* elF = (unsigned short*)(ws + WS_EL);
    float*    esq       = (float*)(ws + WS_ESQ);
    float*    xsq       = (float*)(ws + WS_XSQ);
    unsigned* counts    = (unsigned*)(ws + WS_CNT);
    double*   loss_acc  = (double*)(ws + WS_LOSS);
    unsigned* flag_cnt  = (unsigned*)(ws + WS_FLC);
    int*      sidx      = (int*)(ws + WS_SIDX);
    unsigned* flist     = (unsigned*)(ws + WS_FLIST);
    float*    pm1       = (float*)(ws + WS_PM1);
    float*    pm2       = (float*)(ws + WS_PM2);
    unsigned short* pix = (unsigned short*)(ws + WS_PIX);
    float*    embT      = (float*)(ws + WS_EMBT);

    unsigned short* zhF = (unsigned short*)out;                // [0, 33.5 MB)
    unsigned short* zlF = (unsigned short*)(out + 8388608);    // [33.5, 67 MB)
    float* out_idx = out + OUT_IDX_OFF;

    hipMemsetAsync(ws + WS_CNT, 0, 4108, stream);   // counts + loss + flag_count

    convert_z_kernel<<<1024, 256, 0, stream>>>(z, zhF, zlF);
    convert_e_kernel<<<128, 256, 0, stream>>>(emb, ehF, elF);
    esq_kernel<<<K_CODES / 64, 256, 0, stream>>>(emb, esq);
    xsq_kernel<<<N_VEC / 256, 256, 0, stream>>>(z, xsq);
    screen_kernel<<<2048, 256, 0, stream>>>(zhF, zlF, ehF, elF, esq, xsq, pm1, pm2, pix);
    merge_kernel<<<256, 256, 0, stream>>>(pm1, pm2, pix, sidx, flist, flag_cnt);
    transpose_kernel<<<dim3(16, 4), 256, 0, stream>>>(emb, embT);   // embT overlays pm1
    refine_kernel<<<1024, 256, 0, stream>>>(z, embT, esq, xsq, flist, flag_cnt, out_idx, counts);
    emit_kernel<<<256, 256, 0, stream>>>(sidx, out_idx, counts);
    gather_kernel<<<256, 256, 0, stream>>>(z, embT, out_idx, out, loss_acc);
    finalize_kernel<<<1, 256, 0, stream>>>(counts, loss_acc, out);
}